// Round 4
// baseline (3164.383 us; speedup 1.0000x reference)
//
#include <hip/hip_runtime.h>
#include <stdint.h>

#define H   300
#define HP  320
#define CAP 32     // max incoming bonds per atom (Binomial(400k,1/200k) max ~13)

using bf8 = __attribute__((ext_vector_type(8))) short;   // 8 x bf16
using f4  = __attribute__((ext_vector_type(4))) float;   // MFMA acc

__device__ __forceinline__ float bf2f(unsigned short u){
    union { unsigned int i; float f; } v; v.i = ((unsigned int)u) << 16; return v.f;
}
__device__ __forceinline__ unsigned short f2bf(float x){
    unsigned int u = __builtin_bit_cast(unsigned int, x);
    u = (u + 0x7FFFu + ((u >> 16) & 1u)) >> 16;   // RNE
    return (unsigned short)u;
}

// ---------------------------------------------------------------------------
// Incoming-bond bucket list: bucket[a][0..cnt[a]) = bond indices with dst==a
// ---------------------------------------------------------------------------
__global__ void fill_k(const int* __restrict__ b_dst, int* __restrict__ cnt,
                       int* __restrict__ bucket, int nB){
    int e = blockIdx.x * 256 + threadIdx.x;
    if (e >= nB) return;
    int d = b_dst[e];
    int slot = atomicAdd(&cnt[d], 1);
    if (slot < CAP) bucket[(long)d * CAP + slot] = e;
}

// ---------------------------------------------------------------------------
// Weight prep: W [Kact][H] fp32 -> Wt [320][Kp] bf16, transposed + zero-padded
// ---------------------------------------------------------------------------
__global__ void prep_wt(const float* __restrict__ W, unsigned short* __restrict__ Wt,
                        int Kact, int Kp){
    int idx = blockIdx.x * 256 + threadIdx.x;
    if (idx >= 320 * Kp) return;
    int n = idx / Kp, k = idx % Kp;
    float v = (n < H && k < Kact) ? W[(long)k * H + n] : 0.f;
    Wt[idx] = f2bf(v);
}

// W_o [900][300] -> Wt_o [320][960]: k = blk*320+kk maps to W row blk*300+kk
__global__ void prep_wto(const float* __restrict__ W, unsigned short* __restrict__ Wt){
    int idx = blockIdx.x * 256 + threadIdx.x;
    if (idx >= 320 * 960) return;
    int n = idx / 960, k = idx % 960;
    int blk = k / HP, kk = k % HP;
    float v = (n < H && kk < H) ? W[((long)blk * H + kk) * H + n] : 0.f;
    Wt[idx] = f2bf(v);
}

// ---------------------------------------------------------------------------
// Unified GEMM: out[rows][320] = epilogue( A[rows][K] @ Wt^T )
// A tile (64 x 320) staged into XOR-swizzled LDS once per section.
// B fragments loaded per K-step straight from global (L2-resident weights).
// K-loop has NO barriers; only 2 barriers per section around stageA.
// MODE 0: A = Afp fp32, out = relu(acc)                            (inputs)
// MODE 2: A row e = sum_{incoming(b_src[e])} msg[j] - msg[b2revb[e]],
//         out = relu(bond_in + acc)                                (msg step)
// MODE 3: A = [bfA | bfB | bfA*bfB] (3 sections), out = relu(acc+b_o)
// BM=64, BN=320(all), 256 threads = 4 waves (1M x 4N), 16x16x32 bf16 MFMA
// ---------------------------------------------------------------------------
template<int MODE>
__global__ __launch_bounds__(256, 3)
void gemm_k(const float* __restrict__ Afp, int Kact,
            const unsigned short* __restrict__ Wt,
            const unsigned short* __restrict__ bfA,   // M2: msg_in; M3: input_atom
            const unsigned short* __restrict__ bfB,   // M3: a_msg (bf16)
            const unsigned short* __restrict__ bond_in, // M2: input_bond
            const float* __restrict__ b_o,            // M3
            const int* __restrict__ b_src,
            const int* __restrict__ b2revb,
            const int* __restrict__ cnt,
            const int* __restrict__ bucket,
            unsigned short* __restrict__ outb)        // bf16 [rows][320]
{
    constexpr int KS   = (MODE == 0) ? 5 : 10;        // K-steps per section
    constexpr int SEC  = (MODE == 3) ? 3 : 1;
    constexpr int Ktot = (MODE == 0) ? 160 : (MODE == 3 ? 960 : 320);
    constexpr int TS   = SEC * KS;

    __shared__ char ldsA[64 * 640];                   // 40 KB, XOR-swizzled rows

    const int tid = threadIdx.x;
    const int rowBase = blockIdx.x * 64;
    const int r = tid >> 2, c = tid & 3;              // staged row / k-chunk
    const int e = rowBase + r;

    // byte offset of (row, ushort-col) with bank swizzle (16B-slot granularity)
    auto aoff = [&](int row, int uc)->int {
        return row * 640 + ((uc * 2) ^ ((row & 7) << 4));
    };

    int grev = 0, gbase = 0, gdeg = 0;
    int be0 = 0, be1 = 0, be2 = 0, be3 = 0;
    if constexpr (MODE == 2){
        int s = b_src[e];
        grev  = b2revb[e];
        gbase = s * CAP;
        gdeg  = cnt[s]; if (gdeg > CAP) gdeg = CAP;
        if (gdeg > 0) be0 = bucket[gbase + 0];
        if (gdeg > 1) be1 = bucket[gbase + 1];
        if (gdeg > 2) be2 = bucket[gbase + 2];
        if (gdeg > 3) be3 = bucket[gbase + 3];
    }

    auto stageA = [&](int sec){
        #pragma unroll
        for (int i = 0; i < KS; i++){
            const int kk0 = i * 32 + c * 8;
            bf8 v;
            if constexpr (MODE == 0){
                #pragma unroll
                for (int j = 0; j < 8; j++){
                    int k = kk0 + j;
                    float f = (k < Kact) ? Afp[(long)e * Kact + k] : 0.f;
                    v[j] = (short)f2bf(f);
                }
            } else if constexpr (MODE == 2){
                float accf[8];
                #pragma unroll
                for (int q = 0; q < 8; q++) accf[q] = 0.f;
                auto addrow = [&](int be){
                    bf8 mm = *(const bf8*)(bfA + (long)be * HP + kk0);
                    #pragma unroll
                    for (int q = 0; q < 8; q++) accf[q] += bf2f((unsigned short)mm[q]);
                };
                if (gdeg > 0) addrow(be0);
                if (gdeg > 1) addrow(be1);
                if (gdeg > 2) addrow(be2);
                if (gdeg > 3) addrow(be3);
                for (int j = 4; j < gdeg; ++j) addrow(bucket[gbase + j]);
                bf8 rv = *(const bf8*)(bfA + (long)grev * HP + kk0);
                #pragma unroll
                for (int q = 0; q < 8; q++)
                    v[q] = (short)f2bf(accf[q] - bf2f((unsigned short)rv[q]));
            } else { // MODE 3
                if (sec == 0){
                    v = *(const bf8*)(bfA + (long)e * HP + kk0);
                } else if (sec == 1){
                    v = *(const bf8*)(bfB + (long)e * HP + kk0);
                } else {
                    bf8 a = *(const bf8*)(bfA + (long)e * HP + kk0);
                    bf8 b = *(const bf8*)(bfB + (long)e * HP + kk0);
                    #pragma unroll
                    for (int q = 0; q < 8; q++)
                        v[q] = (short)f2bf(bf2f((unsigned short)a[q]) * bf2f((unsigned short)b[q]));
                }
            }
            *(bf8*)(ldsA + aoff(r, kk0)) = v;
        }
    };

    const int w    = tid >> 6;          // wave -> N stripe of 80
    const int lane = tid & 63;
    const int lr   = lane & 15;
    const int g    = lane >> 4;         // k-subchunk 0..3

    stageA(0);
    __syncthreads();

    f4 acc[4][5];
    #pragma unroll
    for (int m = 0; m < 4; m++)
        #pragma unroll
        for (int n = 0; n < 5; n++)
            acc[m][n] = (f4){0.f, 0.f, 0.f, 0.f};

    for (int t = 0; t < TS; ++t){
        const int ks = t % KS;
        if (ks == 0 && t > 0){           // MODE 3 section boundary
            __syncthreads();             // all waves done reading prev section
            stageA(t / KS);
            __syncthreads();
        }
        // B fragments straight from global (L2-resident weights)
        bf8 bfr[5];
        #pragma unroll
        for (int n = 0; n < 5; n++)
            bfr[n] = *(const bf8*)(Wt + (long)(w * 80 + n * 16 + lr) * Ktot + t * 32 + g * 8);
        bf8 af[4];
        #pragma unroll
        for (int m = 0; m < 4; m++)
            af[m] = *(const bf8*)(ldsA + aoff(m * 16 + lr, ks * 32 + g * 8));
        #pragma unroll
        for (int m = 0; m < 4; m++)
            #pragma unroll
            for (int n = 0; n < 5; n++)
                acc[m][n] = __builtin_amdgcn_mfma_f32_16x16x32_bf16(af[m], bfr[n], acc[m][n], 0, 0, 0);
    }

    // epilogue: C/D layout col = lane&15 (+16*n+80*w), row = (lane>>4)*4 + q
    const int rgrp = g * 4;
    #pragma unroll
    for (int m = 0; m < 4; m++){
        #pragma unroll
        for (int n = 0; n < 5; n++){
            int col = w * 80 + n * 16 + lr;
            #pragma unroll
            for (int q = 0; q < 4; q++){
                int row = m * 16 + rgrp + q;
                int gr  = rowBase + row;
                float v = acc[m][n][q];
                if constexpr (MODE == 2) v += bf2f(bond_in[(long)gr * HP + col]);
                if constexpr (MODE == 3) v += (col < H ? b_o[col] : 0.f);
                v = fmaxf(v, 0.f);
                outb[(long)gr * HP + col] = f2bf(v);
            }
        }
    }
}

// ---------------------------------------------------------------------------
// a_msg[a] = sum of msg rows with dst==a. thread = (atom, 8-col chunk);
// 16B vector loads, bucket preloaded x4 for ILP.
// ---------------------------------------------------------------------------
__global__ __launch_bounds__(256)
void amsg_k(const unsigned short* __restrict__ msg, const int* __restrict__ cnt,
            const int* __restrict__ bucket, unsigned short* __restrict__ amsg,
            int nA){
    int t = blockIdx.x * 256 + threadIdx.x;
    if (t >= nA * 40) return;
    int a = t / 40, ch = t % 40;
    int k0 = ch * 8;
    int dg = cnt[a]; if (dg > CAP) dg = CAP;
    long base = (long)a * CAP;
    int be0 = 0, be1 = 0, be2 = 0, be3 = 0;
    if (dg > 0) be0 = bucket[base + 0];
    if (dg > 1) be1 = bucket[base + 1];
    if (dg > 2) be2 = bucket[base + 2];
    if (dg > 3) be3 = bucket[base + 3];
    float s[8];
    #pragma unroll
    for (int q = 0; q < 8; q++) s[q] = 0.f;
    auto addrow = [&](int be){
        bf8 mm = *(const bf8*)(msg + (long)be * HP + k0);
        #pragma unroll
        for (int q = 0; q < 8; q++) s[q] += bf2f((unsigned short)mm[q]);
    };
    if (dg > 0) addrow(be0);
    if (dg > 1) addrow(be1);
    if (dg > 2) addrow(be2);
    if (dg > 3) addrow(be3);
    for (int j = 4; j < dg; ++j) addrow(bucket[base + j]);
    bf8 v;
    #pragma unroll
    for (int q = 0; q < 8; q++) v[q] = (short)f2bf(s[q]);
    *(bf8*)(amsg + (long)a * HP + k0) = v;
}

// ---------------------------------------------------------------------------
// Readout: per-molecule mean over sorted mol_ids (binary-search range)
// ---------------------------------------------------------------------------
__global__ __launch_bounds__(320)
void readout_k(const unsigned short* __restrict__ atom_h,
               const int* __restrict__ mol_ids, int nAtoms,
               float* __restrict__ out){
    int m = blockIdx.x;
    int t = threadIdx.x;
    int lo = 0, hi = nAtoms;
    while (lo < hi){ int mid = (lo + hi) >> 1; if (mol_ids[mid] < m) lo = mid + 1; else hi = mid; }
    int lo2 = lo, hi2 = nAtoms;
    while (lo2 < hi2){ int mid = (lo2 + hi2) >> 1; if (mol_ids[mid] < m + 1) lo2 = mid + 1; else hi2 = mid; }
    if (t < H){
        float s = 0.f;
        for (int a = lo; a < lo2; ++a) s += bf2f(atom_h[(long)a * HP + t]);
        int c2 = lo2 - lo;
        out[(long)m * H + t] = s / (float)(c2 > 0 ? c2 : 1);
    }
}

// ---------------------------------------------------------------------------
extern "C" void kernel_launch(void* const* d_in, const int* in_sizes, int n_in,
                              void* d_out, int out_size, void* d_ws, size_t ws_size,
                              hipStream_t stream){
    const float* f_atoms  = (const float*)d_in[0];
    const float* f_bonds  = (const float*)d_in[1];
    const float* W_i_atom = (const float*)d_in[2];
    const float* W_i_bond = (const float*)d_in[3];
    const float* W_h      = (const float*)d_in[4];
    const float* W_o      = (const float*)d_in[5];
    const float* b_o      = (const float*)d_in[6];
    const int* b_src   = (const int*)d_in[7];
    const int* b_dst   = (const int*)d_in[8];
    const int* b2revb  = (const int*)d_in[9];
    const int* mol_ids = (const int*)d_in[10];

    const int nA = in_sizes[10];          // 200000 (mol_ids is per-atom)
    const int nB = in_sizes[7];           // 400000
    const int nM = out_size / H;          // 4096

    char* p = (char*)d_ws;
    auto alloc = [&](size_t bytes){ char* q = p; p += (bytes + 255) & ~(size_t)255; return q; };
    unsigned short* Wt_ia = (unsigned short*)alloc((size_t)320 * 160 * 2);
    unsigned short* Wt_ib = (unsigned short*)alloc((size_t)320 * 160 * 2);
    unsigned short* Wt_h  = (unsigned short*)alloc((size_t)3 * 320 * 320 * 2);
    unsigned short* Wt_o  = (unsigned short*)alloc((size_t)320 * 960 * 2);
    int* cnt    = (int*)alloc((size_t)nA * 4);
    int* bucket = (int*)alloc((size_t)nA * CAP * 4);
    unsigned short* input_atom = (unsigned short*)alloc((size_t)nA * HP * 2);
    unsigned short* input_bond = (unsigned short*)alloc((size_t)nB * HP * 2);
    unsigned short* msgA  = (unsigned short*)alloc((size_t)nB * HP * 2);
    unsigned short* msgB  = (unsigned short*)alloc((size_t)nB * HP * 2);
    unsigned short* amsg   = msgB;        // alias: msgB dead after step 3
    unsigned short* atom_h = input_bond;  // alias: input_bond dead after step 3

    if ((size_t)(p - (char*)d_ws) > ws_size) return;  // diagnostic: ws too small

    // adjacency buckets
    hipMemsetAsync(cnt, 0, (size_t)nA * 4, stream);
    fill_k<<<dim3((nB + 255) / 256), dim3(256), 0, stream>>>(b_dst, cnt, bucket, nB);

    // weight prep
    prep_wt<<<dim3((320*160 + 255)/256), dim3(256), 0, stream>>>(W_i_atom, Wt_ia, 133, 160);
    prep_wt<<<dim3((320*160 + 255)/256), dim3(256), 0, stream>>>(W_i_bond, Wt_ib, 147, 160);
    for (int d = 0; d < 3; d++)
        prep_wt<<<dim3((320*320 + 255)/256), dim3(256), 0, stream>>>(
            W_h + (size_t)d * H * H, Wt_h + (size_t)d * 320 * 320, 300, 320);
    prep_wto<<<dim3((320*960 + 255)/256), dim3(256), 0, stream>>>(W_o, Wt_o);

    // input projections
    gemm_k<0><<<dim3(nA/64), dim3(256), 0, stream>>>(
        f_atoms, 133, Wt_ia, nullptr, nullptr, nullptr, nullptr,
        nullptr, nullptr, nullptr, nullptr, input_atom);
    gemm_k<0><<<dim3(nB/64), dim3(256), 0, stream>>>(
        f_bonds, 147, Wt_ib, nullptr, nullptr, nullptr, nullptr,
        nullptr, nullptr, nullptr, nullptr, input_bond);

    // message steps (msg0 = input_bond)
    gemm_k<2><<<dim3(nB/64), dim3(256), 0, stream>>>(
        nullptr, 0, Wt_h + 0 * 320 * 320, input_bond, nullptr, input_bond, nullptr,
        b_src, b2revb, cnt, bucket, msgA);
    gemm_k<2><<<dim3(nB/64), dim3(256), 0, stream>>>(
        nullptr, 0, Wt_h + 1 * 320 * 320, msgA, nullptr, input_bond, nullptr,
        b_src, b2revb, cnt, bucket, msgB);
    gemm_k<2><<<dim3(nB/64), dim3(256), 0, stream>>>(
        nullptr, 0, Wt_h + 2 * 320 * 320, msgB, nullptr, input_bond, nullptr,
        b_src, b2revb, cnt, bucket, msgA);

    // final per-atom aggregation (bf16)
    amsg_k<<<dim3((nA * 40 + 255) / 256), dim3(256), 0, stream>>>(msgA, cnt, bucket, amsg, nA);

    // atom_h = relu([input_atom | amsg | input_atom*amsg] @ W_o + b_o)
    gemm_k<3><<<dim3(nA/64), dim3(256), 0, stream>>>(
        nullptr, 0, Wt_o, input_atom, amsg, nullptr, b_o,
        nullptr, nullptr, nullptr, nullptr, atom_h);

    // per-molecule mean
    readout_k<<<dim3(nM), dim3(320), 0, stream>>>(atom_h, mol_ids, nA, (float*)d_out);
}

// Round 5
// 2322.460 us; speedup vs baseline: 1.3625x; 1.3625x over previous
//
#include <hip/hip_runtime.h>
#include <stdint.h>

#define H   300
#define HP  320
#define CAP 32     // max incoming bonds per atom (Binomial(400k,1/200k) max ~13)

using bf8 = __attribute__((ext_vector_type(8))) short;   // 8 x bf16
using f4  = __attribute__((ext_vector_type(4))) float;   // MFMA acc

__device__ __forceinline__ float bf2f(unsigned short u){
    union { unsigned int i; float f; } v; v.i = ((unsigned int)u) << 16; return v.f;
}
__device__ __forceinline__ unsigned short f2bf(float x){
    unsigned int u = __builtin_bit_cast(unsigned int, x);
    u = (u + 0x7FFFu + ((u >> 16) & 1u)) >> 16;   // RNE
    return (unsigned short)u;
}

// ---------------------------------------------------------------------------
// Incoming-bond bucket list: bucket[a][0..cnt[a]) = bond indices with dst==a
// ---------------------------------------------------------------------------
__global__ void fill_k(const int* __restrict__ b_dst, int* __restrict__ cnt,
                       int* __restrict__ bucket, int nB){
    int e = blockIdx.x * 256 + threadIdx.x;
    if (e >= nB) return;
    int d = b_dst[e];
    int slot = atomicAdd(&cnt[d], 1);
    if (slot < CAP) bucket[(long)d * CAP + slot] = e;
}

// ---------------------------------------------------------------------------
// Weight prep: W [Kact][H] fp32 -> Wt [320][Kp] bf16, transposed + zero-padded
// ---------------------------------------------------------------------------
__global__ void prep_wt(const float* __restrict__ W, unsigned short* __restrict__ Wt,
                        int Kact, int Kp){
    int idx = blockIdx.x * 256 + threadIdx.x;
    if (idx >= 320 * Kp) return;
    int n = idx / Kp, k = idx % Kp;
    float v = (n < H && k < Kact) ? W[(long)k * H + n] : 0.f;
    Wt[idx] = f2bf(v);
}

// W_o [900][300] -> Wt_o [320][960]: k = blk*320+kk maps to W row blk*300+kk
__global__ void prep_wto(const float* __restrict__ W, unsigned short* __restrict__ Wt){
    int idx = blockIdx.x * 256 + threadIdx.x;
    if (idx >= 320 * 960) return;
    int n = idx / 960, k = idx % 960;
    int blk = k / HP, kk = k % HP;
    float v = (n < H && kk < H) ? W[((long)blk * H + kk) * H + n] : 0.f;
    Wt[idx] = f2bf(v);
}

// ---------------------------------------------------------------------------
// Dense GEMM: out[rows][320] = epilogue( A[rows][K] @ Wt^T )
// A tile (64 x 320) staged to XOR-swizzled LDS once per section (sequential).
// B register double-buffered from global (L2-resident weights), K-loop
// barrier-free.
// MODE 0: A fp32 [rows][Kact], out = relu(acc)        (input projections)
// MODE 4: A bf16 [rows][320],  out = acc (raw)        (MW = msg @ W_h)
// MODE 3: A = [bfA | bfB | bfA*bfB] (3 sections), out = relu(acc + b_o)
// BM=64, BN=320(all), 256 threads = 4 waves (1M x 4N), 16x16x32 bf16 MFMA
// ---------------------------------------------------------------------------
template<int MODE>
__global__ __launch_bounds__(256, 3)
void gemm_k(const float* __restrict__ Afp, int Kact,
            const unsigned short* __restrict__ Wt,
            const unsigned short* __restrict__ bfA,   // M4: msg; M3: input_atom
            const unsigned short* __restrict__ bfB,   // M3: a_msg (bf16)
            const float* __restrict__ b_o,            // M3
            unsigned short* __restrict__ outb)        // [rows][320]
{
    constexpr int KS   = (MODE == 0) ? 5 : 10;        // K-steps per section
    constexpr int SEC  = (MODE == 3) ? 3 : 1;
    constexpr int Ktot = (MODE == 0) ? 160 : (MODE == 3 ? 960 : 320);

    __shared__ char ldsA[64 * 640];                   // 40 KB, XOR-swizzled

    const int tid = threadIdx.x;
    const int rowBase = blockIdx.x * 64;
    const int r = tid >> 2, c = tid & 3;              // staged row / k-chunk
    const int e = rowBase + r;

    auto aoff = [&](int row, int uc)->int {           // byte offset, swizzled
        return row * 640 + ((uc * 2) ^ ((row & 7) << 4));
    };

    auto stageA = [&](int sec){
        #pragma unroll
        for (int i = 0; i < KS; i++){
            const int kk0 = i * 32 + c * 8;
            bf8 v;
            if constexpr (MODE == 0){
                #pragma unroll
                for (int j = 0; j < 8; j++){
                    int k = kk0 + j;
                    float f = (k < Kact) ? Afp[(long)e * Kact + k] : 0.f;
                    v[j] = (short)f2bf(f);
                }
            } else if constexpr (MODE == 4){
                v = *(const bf8*)(bfA + (long)e * HP + kk0);
            } else { // MODE 3
                if (sec == 0){
                    v = *(const bf8*)(bfA + (long)e * HP + kk0);
                } else if (sec == 1){
                    v = *(const bf8*)(bfB + (long)e * HP + kk0);
                } else {
                    bf8 a = *(const bf8*)(bfA + (long)e * HP + kk0);
                    bf8 b = *(const bf8*)(bfB + (long)e * HP + kk0);
                    #pragma unroll
                    for (int q = 0; q < 8; q++)
                        v[q] = (short)f2bf(bf2f((unsigned short)a[q]) * bf2f((unsigned short)b[q]));
                }
            }
            *(bf8*)(ldsA + aoff(r, kk0)) = v;
        }
    };

    const int w    = tid >> 6;          // wave -> N stripe of 80
    const int lane = tid & 63;
    const int lr   = lane & 15;
    const int g    = lane >> 4;         // k-subchunk 0..3

    bf8 b0[5], b1[5];
    auto loadB = [&](int t, bf8* dst){
        #pragma unroll
        for (int n = 0; n < 5; n++)
            dst[n] = *(const bf8*)(Wt + (long)(w * 80 + n * 16 + lr) * Ktot + t * 32 + g * 8);
    };

    f4 acc[4][5];
    #pragma unroll
    for (int m = 0; m < 4; m++)
        #pragma unroll
        for (int n = 0; n < 5; n++)
            acc[m][n] = (f4){0.f, 0.f, 0.f, 0.f};

    auto compute = [&](int ks, bf8* bb){
        bf8 af[4];
        #pragma unroll
        for (int m = 0; m < 4; m++)
            af[m] = *(const bf8*)(ldsA + aoff(m * 16 + lr, ks * 32 + g * 8));
        #pragma unroll
        for (int m = 0; m < 4; m++)
            #pragma unroll
            for (int n = 0; n < 5; n++)
                acc[m][n] = __builtin_amdgcn_mfma_f32_16x16x32_bf16(af[m], bb[n], acc[m][n], 0, 0, 0);
    };

    #pragma unroll
    for (int sec = 0; sec < SEC; ++sec){
        if (sec > 0) __syncthreads();    // prev section readers done
        stageA(sec);
        loadB(sec * KS, b0);             // overlaps barrier wait
        __syncthreads();                 // A visible
        #pragma unroll
        for (int i = 0; i < KS; i += 2){
            const int t = sec * KS + i;
            if (i + 1 < KS) loadB(t + 1, b1);
            compute(i, b0);
            if (i + 2 < KS) loadB(t + 2, b0);
            if (i + 1 < KS) compute(i + 1, b1);
        }
    }

    // epilogue: C/D layout col = lane&15 (+16*n+80*w), row = (lane>>4)*4 + q
    const int rgrp = g * 4;
    #pragma unroll
    for (int m = 0; m < 4; m++){
        #pragma unroll
        for (int n = 0; n < 5; n++){
            int col = w * 80 + n * 16 + lr;
            #pragma unroll
            for (int q = 0; q < 4; q++){
                int row = m * 16 + rgrp + q;
                int gr  = rowBase + row;
                float v = acc[m][n][q];
                if constexpr (MODE == 3) v += (col < H ? b_o[col] : 0.f);
                if constexpr (MODE != 4) v = fmaxf(v, 0.f);
                outb[(long)gr * HP + col] = f2bf(v);
            }
        }
    }
}

// ---------------------------------------------------------------------------
// comb: msg'[e] = relu(bond_in[e] + sum_{j in bucket[src[e]]} MW[j] - MW[rev[e]])
// thread = (bond, 8-col chunk); 16B loads, 6 independent loads in flight.
// ---------------------------------------------------------------------------
__global__ __launch_bounds__(256)
void comb_k(const unsigned short* __restrict__ MW,
            const unsigned short* __restrict__ bond_in,
            const int* __restrict__ b_src, const int* __restrict__ b2revb,
            const int* __restrict__ cnt, const int* __restrict__ bucket,
            unsigned short* __restrict__ out, int nB){
    int t = blockIdx.x * 256 + threadIdx.x;
    if (t >= nB * 40) return;
    int e = t / 40, ch = t % 40;
    int k0 = ch * 8;
    int s   = b_src[e];
    int rev = b2revb[e];
    int dg = cnt[s]; if (dg > CAP) dg = CAP;
    long base = (long)s * CAP;
    int be0 = 0, be1 = 0, be2 = 0, be3 = 0;
    if (dg > 0) be0 = bucket[base + 0];
    if (dg > 1) be1 = bucket[base + 1];
    if (dg > 2) be2 = bucket[base + 2];
    if (dg > 3) be3 = bucket[base + 3];
    // issue 6 independent 16B loads
    bf8 bi = *(const bf8*)(bond_in + (long)e * HP + k0);
    bf8 rv = *(const bf8*)(MW + (long)rev * HP + k0);
    bf8 m0, m1, m2, m3;
    if (dg > 0) m0 = *(const bf8*)(MW + (long)be0 * HP + k0);
    if (dg > 1) m1 = *(const bf8*)(MW + (long)be1 * HP + k0);
    if (dg > 2) m2 = *(const bf8*)(MW + (long)be2 * HP + k0);
    if (dg > 3) m3 = *(const bf8*)(MW + (long)be3 * HP + k0);
    float sacc[8];
    #pragma unroll
    for (int q = 0; q < 8; q++)
        sacc[q] = bf2f((unsigned short)bi[q]) - bf2f((unsigned short)rv[q]);
    auto addv = [&](bf8 mm){
        #pragma unroll
        for (int q = 0; q < 8; q++) sacc[q] += bf2f((unsigned short)mm[q]);
    };
    if (dg > 0) addv(m0);
    if (dg > 1) addv(m1);
    if (dg > 2) addv(m2);
    if (dg > 3) addv(m3);
    for (int j = 4; j < dg; ++j){
        int be = bucket[base + j];
        addv(*(const bf8*)(MW + (long)be * HP + k0));
    }
    bf8 v;
    #pragma unroll
    for (int q = 0; q < 8; q++) v[q] = (short)f2bf(fmaxf(sacc[q], 0.f));
    *(bf8*)(out + (long)e * HP + k0) = v;
}

// ---------------------------------------------------------------------------
// a_msg[a] = sum of msg rows with dst==a. thread = (atom, 8-col chunk).
// ---------------------------------------------------------------------------
__global__ __launch_bounds__(256)
void amsg_k(const unsigned short* __restrict__ msg, const int* __restrict__ cnt,
            const int* __restrict__ bucket, unsigned short* __restrict__ amsg,
            int nA){
    int t = blockIdx.x * 256 + threadIdx.x;
    if (t >= nA * 40) return;
    int a = t / 40, ch = t % 40;
    int k0 = ch * 8;
    int dg = cnt[a]; if (dg > CAP) dg = CAP;
    long base = (long)a * CAP;
    int be0 = 0, be1 = 0, be2 = 0, be3 = 0;
    if (dg > 0) be0 = bucket[base + 0];
    if (dg > 1) be1 = bucket[base + 1];
    if (dg > 2) be2 = bucket[base + 2];
    if (dg > 3) be3 = bucket[base + 3];
    bf8 m0, m1, m2, m3;
    if (dg > 0) m0 = *(const bf8*)(msg + (long)be0 * HP + k0);
    if (dg > 1) m1 = *(const bf8*)(msg + (long)be1 * HP + k0);
    if (dg > 2) m2 = *(const bf8*)(msg + (long)be2 * HP + k0);
    if (dg > 3) m3 = *(const bf8*)(msg + (long)be3 * HP + k0);
    float s[8];
    #pragma unroll
    for (int q = 0; q < 8; q++) s[q] = 0.f;
    auto addv = [&](bf8 mm){
        #pragma unroll
        for (int q = 0; q < 8; q++) s[q] += bf2f((unsigned short)mm[q]);
    };
    if (dg > 0) addv(m0);
    if (dg > 1) addv(m1);
    if (dg > 2) addv(m2);
    if (dg > 3) addv(m3);
    for (int j = 4; j < dg; ++j)
        addv(*(const bf8*)(msg + (long)bucket[base + j] * HP + k0));
    bf8 v;
    #pragma unroll
    for (int q = 0; q < 8; q++) v[q] = (short)f2bf(s[q]);
    *(bf8*)(amsg + (long)a * HP + k0) = v;
}

// ---------------------------------------------------------------------------
// Readout: per-molecule mean over sorted mol_ids (binary-search range)
// ---------------------------------------------------------------------------
__global__ __launch_bounds__(320)
void readout_k(const unsigned short* __restrict__ atom_h,
               const int* __restrict__ mol_ids, int nAtoms,
               float* __restrict__ out){
    int m = blockIdx.x;
    int t = threadIdx.x;
    int lo = 0, hi = nAtoms;
    while (lo < hi){ int mid = (lo + hi) >> 1; if (mol_ids[mid] < m) lo = mid + 1; else hi = mid; }
    int lo2 = lo, hi2 = nAtoms;
    while (lo2 < hi2){ int mid = (lo2 + hi2) >> 1; if (mol_ids[mid] < m + 1) lo2 = mid + 1; else hi2 = mid; }
    if (t < H){
        float s = 0.f;
        for (int a = lo; a < lo2; ++a) s += bf2f(atom_h[(long)a * HP + t]);
        int c2 = lo2 - lo;
        out[(long)m * H + t] = s / (float)(c2 > 0 ? c2 : 1);
    }
}

// ---------------------------------------------------------------------------
extern "C" void kernel_launch(void* const* d_in, const int* in_sizes, int n_in,
                              void* d_out, int out_size, void* d_ws, size_t ws_size,
                              hipStream_t stream){
    const float* f_atoms  = (const float*)d_in[0];
    const float* f_bonds  = (const float*)d_in[1];
    const float* W_i_atom = (const float*)d_in[2];
    const float* W_i_bond = (const float*)d_in[3];
    const float* W_h      = (const float*)d_in[4];
    const float* W_o      = (const float*)d_in[5];
    const float* b_o      = (const float*)d_in[6];
    const int* b_src   = (const int*)d_in[7];
    const int* b_dst   = (const int*)d_in[8];
    const int* b2revb  = (const int*)d_in[9];
    const int* mol_ids = (const int*)d_in[10];

    const int nA = in_sizes[10];          // 200000 (mol_ids is per-atom)
    const int nB = in_sizes[7];           // 400000
    const int nM = out_size / H;          // 4096

    char* p = (char*)d_ws;
    auto alloc = [&](size_t bytes){ char* q = p; p += (bytes + 255) & ~(size_t)255; return q; };
    unsigned short* Wt_ia = (unsigned short*)alloc((size_t)320 * 160 * 2);
    unsigned short* Wt_ib = (unsigned short*)alloc((size_t)320 * 160 * 2);
    unsigned short* Wt_h  = (unsigned short*)alloc((size_t)3 * 320 * 320 * 2);
    unsigned short* Wt_o  = (unsigned short*)alloc((size_t)320 * 960 * 2);
    int* cnt    = (int*)alloc((size_t)nA * 4);
    int* bucket = (int*)alloc((size_t)nA * CAP * 4);
    unsigned short* input_atom = (unsigned short*)alloc((size_t)nA * HP * 2);
    unsigned short* input_bond = (unsigned short*)alloc((size_t)nB * HP * 2);
    unsigned short* msgA = (unsigned short*)alloc((size_t)nB * HP * 2);
    unsigned short* MW   = (unsigned short*)alloc((size_t)nB * HP * 2);
    unsigned short* amsg   = MW;          // alias: MW dead after step 3 comb
    unsigned short* atom_h = input_bond;  // alias: input_bond dead after step 3

    if ((size_t)(p - (char*)d_ws) > ws_size) return;  // diagnostic: ws too small

    // adjacency buckets
    hipMemsetAsync(cnt, 0, (size_t)nA * 4, stream);
    fill_k<<<dim3((nB + 255) / 256), dim3(256), 0, stream>>>(b_dst, cnt, bucket, nB);

    // weight prep
    prep_wt<<<dim3((320*160 + 255)/256), dim3(256), 0, stream>>>(W_i_atom, Wt_ia, 133, 160);
    prep_wt<<<dim3((320*160 + 255)/256), dim3(256), 0, stream>>>(W_i_bond, Wt_ib, 147, 160);
    for (int d = 0; d < 3; d++)
        prep_wt<<<dim3((320*320 + 255)/256), dim3(256), 0, stream>>>(
            W_h + (size_t)d * H * H, Wt_h + (size_t)d * 320 * 320, 300, 320);
    prep_wto<<<dim3((320*960 + 255)/256), dim3(256), 0, stream>>>(W_o, Wt_o);

    // input projections
    gemm_k<0><<<dim3(nA/64), dim3(256), 0, stream>>>(
        f_atoms, 133, Wt_ia, nullptr, nullptr, nullptr, input_atom);
    gemm_k<0><<<dim3(nB/64), dim3(256), 0, stream>>>(
        f_bonds, 147, Wt_ib, nullptr, nullptr, nullptr, input_bond);

    // message steps: MW = msg @ W_h[d]; msg' = relu(bond_in + bucket-sum - rev)
    const int combGrid = (nB * 40 + 255) / 256;
    gemm_k<4><<<dim3(nB/64), dim3(256), 0, stream>>>(
        nullptr, 0, Wt_h + 0 * 320 * 320, input_bond, nullptr, nullptr, MW);
    comb_k<<<dim3(combGrid), dim3(256), 0, stream>>>(
        MW, input_bond, b_src, b2revb, cnt, bucket, msgA, nB);
    gemm_k<4><<<dim3(nB/64), dim3(256), 0, stream>>>(
        nullptr, 0, Wt_h + 1 * 320 * 320, msgA, nullptr, nullptr, MW);
    comb_k<<<dim3(combGrid), dim3(256), 0, stream>>>(
        MW, input_bond, b_src, b2revb, cnt, bucket, msgA, nB);
    gemm_k<4><<<dim3(nB/64), dim3(256), 0, stream>>>(
        nullptr, 0, Wt_h + 2 * 320 * 320, msgA, nullptr, nullptr, MW);
    comb_k<<<dim3(combGrid), dim3(256), 0, stream>>>(
        MW, input_bond, b_src, b2revb, cnt, bucket, msgA, nB);

    // final per-atom aggregation (bf16)
    amsg_k<<<dim3((nA * 40 + 255) / 256), dim3(256), 0, stream>>>(msgA, cnt, bucket, amsg, nA);

    // atom_h = relu([input_atom | amsg | input_atom*amsg] @ W_o + b_o)
    gemm_k<3><<<dim3(nA/64), dim3(256), 0, stream>>>(
        nullptr, 0, Wt_o, input_atom, amsg, b_o, atom_h);

    // per-molecule mean
    readout_k<<<dim3(nM), dim3(320), 0, stream>>>(atom_h, mol_ids, nA, (float*)d_out);
}